// Round 1
// baseline (62.588 us; speedup 1.0000x reference)
//
#include <hip/hip_runtime.h>

// Problem constants
#define BB 512      // batch
#define FF 1024     // features (= K of GEMM, also NK*KD)
#define NK 64       // num kernels
#define KD 16       // kernel dim

// ---------------------------------------------------------------------------
// Kernel 1: M = x @ T  (fp32, vector ALU — no fp32 MFMA on CDNA4)
// BM=64, BN=32, BK=16, 128 threads, K split in 2 partials for occupancy.
// grid = (1024/32, 512/64, 2) = (32, 8, 2) = 512 blocks, 2 waves each.
// Each thread computes a 4x4 micro-tile.
// ---------------------------------------------------------------------------
__global__ __launch_bounds__(128) void md_gemm_kernel(
    const float* __restrict__ x, const float* __restrict__ T,
    float* __restrict__ Mout) {
    __shared__ float As[16][68];   // [k][m], pad 68 -> 2-way (free) on transposed writes
    __shared__ float Bs[16][32];   // [k][n]

    const int tid = threadIdx.x;
    const int bn = blockIdx.x * 32;
    const int bm = blockIdx.y * 64;
    const int ks = blockIdx.z;          // K-split index 0..1
    const int k0 = ks * (FF / 2);
    float* out = Mout + (size_t)ks * (BB * FF);

    const int ty = tid >> 3;            // 0..15 -> m_local = ty*4
    const int tx = tid & 7;             // 0..7  -> n_local = tx*4

    const int ar = tid >> 2;            // 0..31 (A stage row)
    const int ac = (tid & 3) * 4;       // 0,4,8,12 (A stage col)
    const int br = tid >> 3;            // 0..15 (B stage row)
    const int bc = (tid & 7) * 4;       // 0..28 (B stage col)

    float acc[4][4] = {};

    for (int it = 0; it < (FF / 2) / 16; ++it) {
        const int kt = k0 + it * 16;
        // global loads first (latency), then LDS writes
        float4 a0 = *(const float4*)&x[(size_t)(bm + ar) * FF + kt + ac];
        float4 a1 = *(const float4*)&x[(size_t)(bm + ar + 32) * FF + kt + ac];
        float4 b0 = *(const float4*)&T[(size_t)(kt + br) * FF + bn + bc];

        As[ac + 0][ar] = a0.x; As[ac + 1][ar] = a0.y;
        As[ac + 2][ar] = a0.z; As[ac + 3][ar] = a0.w;
        As[ac + 0][ar + 32] = a1.x; As[ac + 1][ar + 32] = a1.y;
        As[ac + 2][ar + 32] = a1.z; As[ac + 3][ar + 32] = a1.w;
        *(float4*)&Bs[br][bc] = b0;
        __syncthreads();

        #pragma unroll
        for (int kk = 0; kk < 16; ++kk) {
            float4 a = *(const float4*)&As[kk][ty * 4];
            float4 b = *(const float4*)&Bs[kk][tx * 4];
            const float av[4] = {a.x, a.y, a.z, a.w};
            const float bv[4] = {b.x, b.y, b.z, b.w};
            #pragma unroll
            for (int p = 0; p < 4; ++p)
                #pragma unroll
                for (int q = 0; q < 4; ++q)
                    acc[p][q] = fmaf(av[p], bv[q], acc[p][q]);
        }
        __syncthreads();
    }

    #pragma unroll
    for (int p = 0; p < 4; ++p) {
        float4 v = make_float4(acc[p][0], acc[p][1], acc[p][2], acc[p][3]);
        *(float4*)&out[(size_t)(bm + ty * 4 + p) * FF + bn + tx * 4] = v;
    }
}

// ---------------------------------------------------------------------------
// Kernel 2: out[i,k] = sum_j exp(-sum_d |M[i,k,d]-M[j,k,d]|) - 1
// One block per (k, i-tile of 64). 256 threads = 64 i x 4 j-slices.
// All 512 j-rows of this k staged in LDS (32KB); j is wave-uniform ->
// broadcast ds_reads. M arrives as two K-split partials (M1+M2).
// grid = 64*8 = 512 blocks.
// ---------------------------------------------------------------------------
__global__ __launch_bounds__(256) void md_pairwise_kernel(
    const float* __restrict__ M1, const float* __restrict__ M2,
    float* __restrict__ out) {
    __shared__ float Ms[BB * KD];       // 32 KB: Ms[j][d] for this k
    __shared__ float part[4][64];

    const int k = blockIdx.x >> 3;      // 0..63
    const int tile = blockIdx.x & 7;    // 0..7
    const int t = threadIdx.x;          // 0..255
    const int kbase = k * KD;

    // stage: sum the two K-split partials while loading
    #pragma unroll
    for (int itr = 0; itr < 8; ++itr) {
        int idx = itr * 256 + t;        // float4 index, 0..2047
        int j = idx >> 2;
        int dg = (idx & 3) * 4;
        size_t g = (size_t)j * FF + kbase + dg;
        float4 v1 = *(const float4*)&M1[g];
        float4 v2 = *(const float4*)&M2[g];
        float4 v = make_float4(v1.x + v2.x, v1.y + v2.y, v1.z + v2.z, v1.w + v2.w);
        *(float4*)&Ms[j * KD + dg] = v;
    }
    __syncthreads();

    const int il = t & 63;              // i within tile
    const int slice = t >> 6;           // 0..3 (wave id) -> j-chunk
    const int ig = tile * 64 + il;      // global i

    float mi[16];
    #pragma unroll
    for (int dg = 0; dg < 4; ++dg) {
        float4 v = *(const float4*)&Ms[ig * KD + dg * 4];
        mi[dg * 4 + 0] = v.x; mi[dg * 4 + 1] = v.y;
        mi[dg * 4 + 2] = v.z; mi[dg * 4 + 3] = v.w;
    }

    float acc = 0.0f;
    const int j0 = slice * 128;
    for (int j = j0; j < j0 + 128; ++j) {
        const float4* mj = (const float4*)&Ms[j * KD];
        float4 v0 = mj[0], v1 = mj[1], v2 = mj[2], v3 = mj[3];
        // balanced tree for short dependency chain
        float p0 = (fabsf(mi[0] - v0.x) + fabsf(mi[1] - v0.y)) +
                   (fabsf(mi[2] - v0.z) + fabsf(mi[3] - v0.w));
        float p1 = (fabsf(mi[4] - v1.x) + fabsf(mi[5] - v1.y)) +
                   (fabsf(mi[6] - v1.z) + fabsf(mi[7] - v1.w));
        float p2 = (fabsf(mi[8] - v2.x) + fabsf(mi[9] - v2.y)) +
                   (fabsf(mi[10] - v2.z) + fabsf(mi[11] - v2.w));
        float p3 = (fabsf(mi[12] - v3.x) + fabsf(mi[13] - v3.y)) +
                   (fabsf(mi[14] - v3.z) + fabsf(mi[15] - v3.w));
        float l1 = (p0 + p1) + (p2 + p3);
        acc += __expf(-l1);
    }

    part[slice][il] = acc;
    __syncthreads();
    if (t < 64) {
        float s = ((part[0][t] + part[1][t]) + (part[2][t] + part[3][t])) - 1.0f;
        out[(size_t)(tile * 64 + t) * NK + k] = s;
    }
}

extern "C" void kernel_launch(void* const* d_in, const int* in_sizes, int n_in,
                              void* d_out, int out_size, void* d_ws, size_t ws_size,
                              hipStream_t stream) {
    const float* x = (const float*)d_in[0];   // [512, 1024]
    const float* T = (const float*)d_in[1];   // [1024, 1024]
    float* out = (float*)d_out;               // [512, 64]

    float* M1 = (float*)d_ws;                 // [512, 1024] partial (K 0..511)
    float* M2 = M1 + (size_t)BB * FF;         // [512, 1024] partial (K 512..1023)

    md_gemm_kernel<<<dim3(FF / 32, BB / 64, 2), 128, 0, stream>>>(x, T, M1);
    md_pairwise_kernel<<<dim3(NK * 8), 256, 0, stream>>>(M1, M2, out);
}

// Round 2
// 50.937 us; speedup vs baseline: 1.2287x; 1.2287x over previous
//
#include <hip/hip_runtime.h>
#include <hip/hip_bf16.h>

// Problem constants
#define BB 512      // batch
#define FF 1024     // features (= K of GEMM, = NK*KD)
#define NK 64       // num kernels
#define KD 16       // kernel dim

typedef __attribute__((ext_vector_type(4))) float f32x4;
typedef __attribute__((ext_vector_type(8))) short short8;

__device__ __forceinline__ unsigned short bf16_hi(float f) {
    __hip_bfloat16 h = __float2bfloat16(f);   // RNE
    return *reinterpret_cast<unsigned short*>(&h);
}
__device__ __forceinline__ float bf16_back(unsigned short u) {
    __hip_bfloat16 h = *reinterpret_cast<__hip_bfloat16*>(&u);
    return __bfloat162float(h);
}

// ---------------------------------------------------------------------------
// Prep: xh/xl = split-bf16 of x [512][1024] (k-contiguous already);
//       Th/Tl = split-bf16 of T TRANSPOSED to [n][k] so GEMM B-frags are
//       k-contiguous. Blocks 0..255: T 64x64 transpose tiles. 256..383: x.
// ---------------------------------------------------------------------------
__global__ __launch_bounds__(256) void md_prep_kernel(
    const float* __restrict__ x, const float* __restrict__ T,
    unsigned short* __restrict__ xh, unsigned short* __restrict__ xl,
    unsigned short* __restrict__ Th, unsigned short* __restrict__ Tl) {
    const int b = blockIdx.x;
    const int t = threadIdx.x;
    if (b < 256) {
        __shared__ float tile[64][65];   // pad 65: transposed reads 2-way (free)
        const int k0 = (b >> 4) * 64, n0 = (b & 15) * 64;
        #pragma unroll
        for (int rr = 0; rr < 4; ++rr) {
            const int kk = rr * 16 + (t >> 4);
            const float4 v = *(const float4*)&T[(size_t)(k0 + kk) * FF + n0 + (t & 15) * 4];
            tile[kk][(t & 15) * 4 + 0] = v.x; tile[kk][(t & 15) * 4 + 1] = v.y;
            tile[kk][(t & 15) * 4 + 2] = v.z; tile[kk][(t & 15) * 4 + 3] = v.w;
        }
        __syncthreads();
        #pragma unroll
        for (int rr = 0; rr < 4; ++rr) {
            const int nl = rr * 16 + (t >> 4);
            const int kl = (t & 15) * 4;
            ushort4 h, l;
            float f0 = tile[kl + 0][nl], f1 = tile[kl + 1][nl];
            float f2 = tile[kl + 2][nl], f3 = tile[kl + 3][nl];
            h.x = bf16_hi(f0); l.x = bf16_hi(f0 - bf16_back(h.x));
            h.y = bf16_hi(f1); l.y = bf16_hi(f1 - bf16_back(h.y));
            h.z = bf16_hi(f2); l.z = bf16_hi(f2 - bf16_back(h.z));
            h.w = bf16_hi(f3); l.w = bf16_hi(f3 - bf16_back(h.w));
            const size_t o = (size_t)(n0 + nl) * FF + k0 + kl;
            *(ushort4*)&Th[o] = h;
            *(ushort4*)&Tl[o] = l;
        }
    } else {
        // x conversion: 131072 float4 over 128 blocks x 256 thr x 4
        const int base = (b - 256) * 256 + t;
        #pragma unroll
        for (int s = 0; s < 4; ++s) {
            const int idx = s * 32768 + base;    // float4 index
            const float4 v = *(const float4*)&x[(size_t)idx * 4];
            ushort4 h, l;
            h.x = bf16_hi(v.x); l.x = bf16_hi(v.x - bf16_back(h.x));
            h.y = bf16_hi(v.y); l.y = bf16_hi(v.y - bf16_back(h.y));
            h.z = bf16_hi(v.z); l.z = bf16_hi(v.z - bf16_back(h.z));
            h.w = bf16_hi(v.w); l.w = bf16_hi(v.w - bf16_back(h.w));
            *(ushort4*)&xh[(size_t)idx * 4] = h;
            *(ushort4*)&xl[(size_t)idx * 4] = l;
        }
    }
}

// ---------------------------------------------------------------------------
// MFMA GEMM: M = x@T via split-bf16, 3 products (hh, hl, lh).
// BM=BN=64, BK=32, split-K 4 -> grid (16,8,4)=512 blocks, 256 thr (4 waves).
// Wave w stages one of {Ah,Al,Bh,Bl} via global_load_lds(16B) and computes
// one 32x32 quadrant (2x2 frags of 16x16x32).
// ---------------------------------------------------------------------------
__global__ __launch_bounds__(256) void md_mfma_kernel(
    const unsigned short* __restrict__ xh, const unsigned short* __restrict__ xl,
    const unsigned short* __restrict__ Th, const unsigned short* __restrict__ Tl,
    float* __restrict__ Mp) {
    __shared__ unsigned short lds[4][64 * 32];   // Ah, Al, Bh, Bl: [row][k] 64B rows
    const int t = threadIdx.x;
    const int w = t >> 6, l = t & 63;
    const int bn = blockIdx.x * 64, bm = blockIdx.y * 64;
    const int kz = blockIdx.z * 256;
    float* out = Mp + (size_t)blockIdx.z * (BB * FF);

    const unsigned short* mysrc =
        (w == 0) ? xh + (size_t)bm * FF :
        (w == 1) ? xl + (size_t)bm * FF :
        (w == 2) ? Th + (size_t)bn * FF :
                   Tl + (size_t)bn * FF;

    f32x4 acc[2][2] = {};
    const int m0 = (w >> 1) * 32, n0 = (w & 1) * 32;
    const int lrow = l & 15;
    const int lk = (l >> 4) * 8;     // assumed (symmetric) k-map: k = (l>>4)*8 + e

    for (int it = 0; it < 8; ++it) {
        const int kt = kz + it * 32;
        #pragma unroll
        for (int q = 0; q < 4; ++q) {
            const int r = q * 16 + (l >> 2);
            const unsigned short* g = mysrc + (size_t)r * FF + kt + (l & 3) * 8;
            __builtin_amdgcn_global_load_lds(
                (const __attribute__((address_space(1))) void*)g,
                (__attribute__((address_space(3))) void*)&lds[w][q * 512],
                16, 0, 0);
        }
        __syncthreads();

        short8 ah[2], al[2], bh[2], bl[2];
        #pragma unroll
        for (int i = 0; i < 2; ++i) {
            const int arow = m0 + i * 16 + lrow;
            ah[i] = *(const short8*)&lds[0][arow * 32 + lk];
            al[i] = *(const short8*)&lds[1][arow * 32 + lk];
            const int brow = n0 + i * 16 + lrow;
            bh[i] = *(const short8*)&lds[2][brow * 32 + lk];
            bl[i] = *(const short8*)&lds[3][brow * 32 + lk];
        }
        #pragma unroll
        for (int i = 0; i < 2; ++i)
            #pragma unroll
            for (int j = 0; j < 2; ++j) {
                acc[i][j] = __builtin_amdgcn_mfma_f32_16x16x32_bf16(ah[i], bh[j], acc[i][j], 0, 0, 0);
                acc[i][j] = __builtin_amdgcn_mfma_f32_16x16x32_bf16(ah[i], bl[j], acc[i][j], 0, 0, 0);
                acc[i][j] = __builtin_amdgcn_mfma_f32_16x16x32_bf16(al[i], bh[j], acc[i][j], 0, 0, 0);
            }
        __syncthreads();
    }

    // C/D layout (m89-verified): col = lane&15, row = (lane>>4)*4 + reg
    #pragma unroll
    for (int i = 0; i < 2; ++i)
        #pragma unroll
        for (int j = 0; j < 2; ++j) {
            const int col = bn + n0 + j * 16 + (l & 15);
            const int rbase = bm + m0 + i * 16 + (l >> 4) * 4;
            #pragma unroll
            for (int rg = 0; rg < 4; ++rg)
                out[(size_t)(rbase + rg) * FF + col] = acc[i][j][rg];
        }
}

// ---------------------------------------------------------------------------
// Pairwise: out[i,k] = sum_j exp(-sum_d |M[i,k,d]-M[j,k,d]|) - 1
// Block = (k, i-tile of 64), 512 threads = 64 i x 8 j-slices.
// Stages all 512 j-rows of k in LDS, summing the 4 split-K partials.
// ---------------------------------------------------------------------------
__global__ __launch_bounds__(512) void md_pairwise_kernel(
    const float* __restrict__ Mp, float* __restrict__ out) {
    __shared__ float Ms[BB * KD];        // 32 KB
    __shared__ float part[8][64];

    const int k = blockIdx.x >> 3;
    const int tile = blockIdx.x & 7;
    const int t = threadIdx.x;
    const int kbase = k * KD;
    const size_t P = (size_t)BB * FF;

    #pragma unroll
    for (int s = 0; s < 4; ++s) {
        const int idx = s * 512 + t;     // float4 idx 0..2047
        const int j = idx >> 2;
        const int dg = (idx & 3) * 4;
        const size_t g = (size_t)j * FF + kbase + dg;
        const float4 v0 = *(const float4*)&Mp[g];
        const float4 v1 = *(const float4*)&Mp[g + P];
        const float4 v2 = *(const float4*)&Mp[g + 2 * P];
        const float4 v3 = *(const float4*)&Mp[g + 3 * P];
        *(float4*)&Ms[j * KD + dg] = make_float4(
            v0.x + v1.x + v2.x + v3.x, v0.y + v1.y + v2.y + v3.y,
            v0.z + v1.z + v2.z + v3.z, v0.w + v1.w + v2.w + v3.w);
    }
    __syncthreads();

    const int il = t & 63;
    const int slice = t >> 6;
    const int ig = tile * 64 + il;

    float mi[16];
    #pragma unroll
    for (int dg = 0; dg < 4; ++dg) {
        const float4 v = *(const float4*)&Ms[ig * KD + dg * 4];
        mi[dg * 4 + 0] = v.x; mi[dg * 4 + 1] = v.y;
        mi[dg * 4 + 2] = v.z; mi[dg * 4 + 3] = v.w;
    }

    float acc = 0.0f;
    const int j0 = slice * 64;
    for (int j = j0; j < j0 + 64; ++j) {
        const float4* mj = (const float4*)&Ms[j * KD];
        const float4 v0 = mj[0], v1 = mj[1], v2 = mj[2], v3 = mj[3];
        float p0 = (fabsf(mi[0] - v0.x) + fabsf(mi[1] - v0.y)) +
                   (fabsf(mi[2] - v0.z) + fabsf(mi[3] - v0.w));
        float p1 = (fabsf(mi[4] - v1.x) + fabsf(mi[5] - v1.y)) +
                   (fabsf(mi[6] - v1.z) + fabsf(mi[7] - v1.w));
        float p2 = (fabsf(mi[8] - v2.x) + fabsf(mi[9] - v2.y)) +
                   (fabsf(mi[10] - v2.z) + fabsf(mi[11] - v2.w));
        float p3 = (fabsf(mi[12] - v3.x) + fabsf(mi[13] - v3.y)) +
                   (fabsf(mi[14] - v3.z) + fabsf(mi[15] - v3.w));
        acc += __expf(-((p0 + p1) + (p2 + p3)));
    }

    part[slice][il] = acc;
    __syncthreads();
    if (t < 64) {
        float s = ((part[0][t] + part[1][t]) + (part[2][t] + part[3][t])) +
                  ((part[4][t] + part[5][t]) + (part[6][t] + part[7][t])) - 1.0f;
        out[(size_t)(tile * 64 + t) * NK + k] = s;
    }
}

extern "C" void kernel_launch(void* const* d_in, const int* in_sizes, int n_in,
                              void* d_out, int out_size, void* d_ws, size_t ws_size,
                              hipStream_t stream) {
    const float* x = (const float*)d_in[0];   // [512, 1024] f32
    const float* T = (const float*)d_in[1];   // [1024, 1024] f32
    float* out = (float*)d_out;               // [512, 64] f32

    unsigned short* xh = (unsigned short*)d_ws;         // 512x1024 bf16
    unsigned short* xl = xh + (size_t)BB * FF;
    unsigned short* Th = xl + (size_t)BB * FF;          // 1024x1024 bf16 [n][k]
    unsigned short* Tl = Th + (size_t)FF * FF;
    float* Mp = (float*)(Tl + (size_t)FF * FF);         // 4 x [512][1024] f32 partials

    md_prep_kernel<<<384, 256, 0, stream>>>(x, T, xh, xl, Th, Tl);
    md_mfma_kernel<<<dim3(16, 8, 4), 256, 0, stream>>>(xh, xl, Th, Tl, Mp);
    md_pairwise_kernel<<<dim3(NK * 8), 512, 0, stream>>>(Mp, out);
}

// Round 3
// 44.219 us; speedup vs baseline: 1.4154x; 1.1519x over previous
//
#include <hip/hip_runtime.h>
#include <hip/hip_bf16.h>

// Problem constants
#define BB 512      // batch
#define FF 1024     // features (= K of GEMM, = NK*KD)
#define NK 64       // num kernels
#define KD 16       // kernel dim

typedef __attribute__((ext_vector_type(4))) float f32x4;
typedef __attribute__((ext_vector_type(8))) short short8;

__device__ __forceinline__ unsigned short bf16_hi(float f) {
    __hip_bfloat16 h = __float2bfloat16(f);   // RNE
    return *reinterpret_cast<unsigned short*>(&h);
}
__device__ __forceinline__ float bf16_back(unsigned short u) {
    __hip_bfloat16 h = *reinterpret_cast<__hip_bfloat16*>(&u);
    return __bfloat162float(h);
}

// ---------------------------------------------------------------------------
// Prep: xh/xl = split-bf16 of x [512][1024] (k-contiguous already);
//       Th/Tl = split-bf16 of T TRANSPOSED to [n][k].
// ---------------------------------------------------------------------------
__global__ __launch_bounds__(256) void md_prep_kernel(
    const float* __restrict__ x, const float* __restrict__ T,
    unsigned short* __restrict__ xh, unsigned short* __restrict__ xl,
    unsigned short* __restrict__ Th, unsigned short* __restrict__ Tl) {
    const int b = blockIdx.x;
    const int t = threadIdx.x;
    if (b < 256) {
        __shared__ float tile[64][65];
        const int k0 = (b >> 4) * 64, n0 = (b & 15) * 64;
        #pragma unroll
        for (int rr = 0; rr < 4; ++rr) {
            const int kk = rr * 16 + (t >> 4);
            const float4 v = *(const float4*)&T[(size_t)(k0 + kk) * FF + n0 + (t & 15) * 4];
            tile[kk][(t & 15) * 4 + 0] = v.x; tile[kk][(t & 15) * 4 + 1] = v.y;
            tile[kk][(t & 15) * 4 + 2] = v.z; tile[kk][(t & 15) * 4 + 3] = v.w;
        }
        __syncthreads();
        #pragma unroll
        for (int rr = 0; rr < 4; ++rr) {
            const int nl = rr * 16 + (t >> 4);
            const int kl = (t & 15) * 4;
            ushort4 h, l;
            float f0 = tile[kl + 0][nl], f1 = tile[kl + 1][nl];
            float f2 = tile[kl + 2][nl], f3 = tile[kl + 3][nl];
            h.x = bf16_hi(f0); l.x = bf16_hi(f0 - bf16_back(h.x));
            h.y = bf16_hi(f1); l.y = bf16_hi(f1 - bf16_back(h.y));
            h.z = bf16_hi(f2); l.z = bf16_hi(f2 - bf16_back(h.z));
            h.w = bf16_hi(f3); l.w = bf16_hi(f3 - bf16_back(h.w));
            const size_t o = (size_t)(n0 + nl) * FF + k0 + kl;
            *(ushort4*)&Th[o] = h;
            *(ushort4*)&Tl[o] = l;
        }
    } else {
        const int base = (b - 256) * 256 + t;
        #pragma unroll
        for (int s = 0; s < 4; ++s) {
            const int idx = s * 32768 + base;
            const float4 v = *(const float4*)&x[(size_t)idx * 4];
            ushort4 h, l;
            h.x = bf16_hi(v.x); l.x = bf16_hi(v.x - bf16_back(h.x));
            h.y = bf16_hi(v.y); l.y = bf16_hi(v.y - bf16_back(h.y));
            h.z = bf16_hi(v.z); l.z = bf16_hi(v.z - bf16_back(h.z));
            h.w = bf16_hi(v.w); l.w = bf16_hi(v.w - bf16_back(h.w));
            *(ushort4*)&xh[(size_t)idx * 4] = h;
            *(ushort4*)&xl[(size_t)idx * 4] = l;
        }
    }
}

// ---------------------------------------------------------------------------
// MFMA GEMM: M = x@T via split-bf16 (hh + hl + lh), split-K 4 partials.
// (unchanged from R2 — verified correct)
// ---------------------------------------------------------------------------
__global__ __launch_bounds__(256) void md_mfma_kernel(
    const unsigned short* __restrict__ xh, const unsigned short* __restrict__ xl,
    const unsigned short* __restrict__ Th, const unsigned short* __restrict__ Tl,
    float* __restrict__ Mp) {
    __shared__ unsigned short lds[4][64 * 32];
    const int t = threadIdx.x;
    const int w = t >> 6, l = t & 63;
    const int bn = blockIdx.x * 64, bm = blockIdx.y * 64;
    const int kz = blockIdx.z * 256;
    float* out = Mp + (size_t)blockIdx.z * (BB * FF);

    const unsigned short* mysrc =
        (w == 0) ? xh + (size_t)bm * FF :
        (w == 1) ? xl + (size_t)bm * FF :
        (w == 2) ? Th + (size_t)bn * FF :
                   Tl + (size_t)bn * FF;

    f32x4 acc[2][2] = {};
    const int m0 = (w >> 1) * 32, n0 = (w & 1) * 32;
    const int lrow = l & 15;
    const int lk = (l >> 4) * 8;

    for (int it = 0; it < 8; ++it) {
        const int kt = kz + it * 32;
        #pragma unroll
        for (int q = 0; q < 4; ++q) {
            const int r = q * 16 + (l >> 2);
            const unsigned short* g = mysrc + (size_t)r * FF + kt + (l & 3) * 8;
            __builtin_amdgcn_global_load_lds(
                (const __attribute__((address_space(1))) void*)g,
                (__attribute__((address_space(3))) void*)&lds[w][q * 512],
                16, 0, 0);
        }
        __syncthreads();

        short8 ah[2], al[2], bh[2], bl[2];
        #pragma unroll
        for (int i = 0; i < 2; ++i) {
            const int arow = m0 + i * 16 + lrow;
            ah[i] = *(const short8*)&lds[0][arow * 32 + lk];
            al[i] = *(const short8*)&lds[1][arow * 32 + lk];
            const int brow = n0 + i * 16 + lrow;
            bh[i] = *(const short8*)&lds[2][brow * 32 + lk];
            bl[i] = *(const short8*)&lds[3][brow * 32 + lk];
        }
        #pragma unroll
        for (int i = 0; i < 2; ++i)
            #pragma unroll
            for (int j = 0; j < 2; ++j) {
                acc[i][j] = __builtin_amdgcn_mfma_f32_16x16x32_bf16(ah[i], bh[j], acc[i][j], 0, 0, 0);
                acc[i][j] = __builtin_amdgcn_mfma_f32_16x16x32_bf16(ah[i], bl[j], acc[i][j], 0, 0, 0);
                acc[i][j] = __builtin_amdgcn_mfma_f32_16x16x32_bf16(al[i], bh[j], acc[i][j], 0, 0, 0);
            }
        __syncthreads();
    }

    #pragma unroll
    for (int i = 0; i < 2; ++i)
        #pragma unroll
        for (int j = 0; j < 2; ++j) {
            const int col = bn + n0 + j * 16 + (l & 15);
            const int rbase = bm + m0 + i * 16 + (l >> 4) * 4;
            #pragma unroll
            for (int rg = 0; rg < 4; ++rg)
                out[(size_t)(rbase + rg) * FF + col] = acc[i][j][rg];
        }
}

// ---------------------------------------------------------------------------
// Symmetric pairwise: upper-tri 64x64 tile-pairs (36) x 64 k = 2304 blocks.
// Each block: stage Mi,Mj (sum 4 split-K partials), compute exp(-l1) for
// all 64x64 pairs (16 per thread), accumulate row sums (regs) + col sums
// (exp-tile in LDS, reduced), atomicAdd both into zeroed out. Diagonal
// blocks skip the col pass and fold in the -1.
// ---------------------------------------------------------------------------
__global__ __launch_bounds__(256) void md_pairwise_sym_kernel(
    const float* __restrict__ Mp, float* __restrict__ out) {
    __shared__ float Mi[64][16];         // 4 KB
    __shared__ float Mj[64][16];         // 4 KB
    __shared__ float et[64][65];         // exp tile, padded: (i+j)%32 banks
    __shared__ float part_row[4][64];
    __shared__ float part_col[4][64];

    const int bx = blockIdx.x;
    const int k = bx & 63;
    int p = bx >> 6;                     // 0..35 upper-tri pair index
    int it = 0;
    while (p >= 8 - it) { p -= 8 - it; ++it; }
    const int jt = it + p;
    const bool diag = (it == jt);

    const int t = threadIdx.x;
    const size_t P = (size_t)BB * FF;
    const int kbase = k * KD;

    // stage Mi, Mj: one float4 per thread per tile, summing 4 partials
    {
        const int row = t >> 2, dg = (t & 3) * 4;
        const size_t gi = (size_t)(it * 64 + row) * FF + kbase + dg;
        const size_t gj = (size_t)(jt * 64 + row) * FF + kbase + dg;
        float4 a0 = *(const float4*)&Mp[gi];
        float4 a1 = *(const float4*)&Mp[gi + P];
        float4 a2 = *(const float4*)&Mp[gi + 2 * P];
        float4 a3 = *(const float4*)&Mp[gi + 3 * P];
        *(float4*)&Mi[row][dg] = make_float4(
            a0.x + a1.x + a2.x + a3.x, a0.y + a1.y + a2.y + a3.y,
            a0.z + a1.z + a2.z + a3.z, a0.w + a1.w + a2.w + a3.w);
        float4 b0 = *(const float4*)&Mp[gj];
        float4 b1 = *(const float4*)&Mp[gj + P];
        float4 b2 = *(const float4*)&Mp[gj + 2 * P];
        float4 b3 = *(const float4*)&Mp[gj + 3 * P];
        *(float4*)&Mj[row][dg] = make_float4(
            b0.x + b1.x + b2.x + b3.x, b0.y + b1.y + b2.y + b3.y,
            b0.z + b1.z + b2.z + b3.z, b0.w + b1.w + b2.w + b3.w);
    }
    __syncthreads();

    const int i = t & 63;                // my row within i-tile (= lane)
    const int wv = t >> 6;               // wave id -> j-chunk of 16

    float mi[16];
    #pragma unroll
    for (int dg = 0; dg < 4; ++dg) {
        const float4 v = *(const float4*)&Mi[i][dg * 4];
        mi[dg * 4 + 0] = v.x; mi[dg * 4 + 1] = v.y;
        mi[dg * 4 + 2] = v.z; mi[dg * 4 + 3] = v.w;
    }

    float row_acc = 0.0f;
    #pragma unroll 4
    for (int jj = 0; jj < 16; ++jj) {
        const int j = wv * 16 + jj;      // wave-uniform -> broadcast reads
        const float4* mj = (const float4*)&Mj[j][0];
        const float4 v0 = mj[0], v1 = mj[1], v2 = mj[2], v3 = mj[3];
        float p0 = (fabsf(mi[0] - v0.x) + fabsf(mi[1] - v0.y)) +
                   (fabsf(mi[2] - v0.z) + fabsf(mi[3] - v0.w));
        float p1 = (fabsf(mi[4] - v1.x) + fabsf(mi[5] - v1.y)) +
                   (fabsf(mi[6] - v1.z) + fabsf(mi[7] - v1.w));
        float p2 = (fabsf(mi[8] - v2.x) + fabsf(mi[9] - v2.y)) +
                   (fabsf(mi[10] - v2.z) + fabsf(mi[11] - v2.w));
        float p3 = (fabsf(mi[12] - v3.x) + fabsf(mi[13] - v3.y)) +
                   (fabsf(mi[14] - v3.z) + fabsf(mi[15] - v3.w));
        const float e = __expf(-((p0 + p1) + (p2 + p3)));
        row_acc += e;
        et[i][j] = e;                    // banks (i+j)%32 -> 2-way, free
    }
    part_row[wv][i] = row_acc;
    __syncthreads();

    float col_acc = 0.0f;
    if (!diag) {
        const int j = t & 63;
        const int chunk = t >> 6;
        #pragma unroll
        for (int ii = 0; ii < 16; ++ii)
            col_acc += et[chunk * 16 + ii][j];   // banks (ii+j)%32 -> 2-way
        part_col[chunk][j] = col_acc;
    }
    __syncthreads();

    if (t < 64) {
        float r = ((part_row[0][t] + part_row[1][t]) +
                   (part_row[2][t] + part_row[3][t])) - (diag ? 1.0f : 0.0f);
        atomicAdd(&out[(size_t)(it * 64 + t) * NK + k], r);
    } else if (t < 128 && !diag) {
        const int j = t - 64;
        float c = (part_col[0][j] + part_col[1][j]) +
                  (part_col[2][j] + part_col[3][j]);
        atomicAdd(&out[(size_t)(jt * 64 + j) * NK + k], c);
    }
}

extern "C" void kernel_launch(void* const* d_in, const int* in_sizes, int n_in,
                              void* d_out, int out_size, void* d_ws, size_t ws_size,
                              hipStream_t stream) {
    const float* x = (const float*)d_in[0];   // [512, 1024] f32
    const float* T = (const float*)d_in[1];   // [1024, 1024] f32
    float* out = (float*)d_out;               // [512, 64] f32

    unsigned short* xh = (unsigned short*)d_ws;         // 512x1024 bf16
    unsigned short* xl = xh + (size_t)BB * FF;
    unsigned short* Th = xl + (size_t)BB * FF;          // 1024x1024 bf16 [n][k]
    unsigned short* Tl = Th + (size_t)FF * FF;
    float* Mp = (float*)(Tl + (size_t)FF * FF);         // 4 x [512][1024] f32

    hipMemsetAsync(out, 0, (size_t)out_size * sizeof(float), stream);
    md_prep_kernel<<<384, 256, 0, stream>>>(x, T, xh, xl, Th, Tl);
    md_mfma_kernel<<<dim3(16, 8, 4), 256, 0, stream>>>(xh, xl, Th, Tl, Mp);
    md_pairwise_sym_kernel<<<dim3(36 * 64), 256, 0, stream>>>(Mp, out);
}

// Round 4
// 38.133 us; speedup vs baseline: 1.6413x; 1.1596x over previous
//
#include <hip/hip_runtime.h>
#include <hip/hip_bf16.h>

// Problem constants
#define BB 512      // batch
#define FF 1024     // features (= K of GEMM, = NK*KD)
#define NK 64       // num kernels
#define KD 16       // kernel dim

typedef __attribute__((ext_vector_type(4))) float f32x4;
typedef __attribute__((ext_vector_type(8))) short short8;

__device__ __forceinline__ unsigned short bf16_hi(float f) {
    __hip_bfloat16 h = __float2bfloat16(f);   // RNE
    return *reinterpret_cast<unsigned short*>(&h);
}
__device__ __forceinline__ float bf16_back(unsigned short u) {
    __hip_bfloat16 h = *reinterpret_cast<__hip_bfloat16*>(&u);
    return __bfloat162float(h);
}

// ---------------------------------------------------------------------------
// Prep: blocks 0..255  : T 64x64 transpose tiles -> Th/Tl [n][k] split-bf16
//       blocks 256..383: x -> xh/xl split-bf16
//       blocks 384..385: zero `out` (replaces hipMemsetAsync dispatch)
// ---------------------------------------------------------------------------
__global__ __launch_bounds__(256) void md_prep_kernel(
    const float* __restrict__ x, const float* __restrict__ T,
    unsigned short* __restrict__ xh, unsigned short* __restrict__ xl,
    unsigned short* __restrict__ Th, unsigned short* __restrict__ Tl,
    float* __restrict__ out) {
    const int b = blockIdx.x;
    const int t = threadIdx.x;
    if (b < 256) {
        __shared__ float tile[64][65];
        const int k0 = (b >> 4) * 64, n0 = (b & 15) * 64;
        #pragma unroll
        for (int rr = 0; rr < 4; ++rr) {
            const int kk = rr * 16 + (t >> 4);
            const float4 v = *(const float4*)&T[(size_t)(k0 + kk) * FF + n0 + (t & 15) * 4];
            tile[kk][(t & 15) * 4 + 0] = v.x; tile[kk][(t & 15) * 4 + 1] = v.y;
            tile[kk][(t & 15) * 4 + 2] = v.z; tile[kk][(t & 15) * 4 + 3] = v.w;
        }
        __syncthreads();
        #pragma unroll
        for (int rr = 0; rr < 4; ++rr) {
            const int nl = rr * 16 + (t >> 4);
            const int kl = (t & 15) * 4;
            ushort4 h, l;
            float f0 = tile[kl + 0][nl], f1 = tile[kl + 1][nl];
            float f2 = tile[kl + 2][nl], f3 = tile[kl + 3][nl];
            h.x = bf16_hi(f0); l.x = bf16_hi(f0 - bf16_back(h.x));
            h.y = bf16_hi(f1); l.y = bf16_hi(f1 - bf16_back(h.y));
            h.z = bf16_hi(f2); l.z = bf16_hi(f2 - bf16_back(h.z));
            h.w = bf16_hi(f3); l.w = bf16_hi(f3 - bf16_back(h.w));
            const size_t o = (size_t)(n0 + nl) * FF + k0 + kl;
            *(ushort4*)&Th[o] = h;
            *(ushort4*)&Tl[o] = l;
        }
    } else if (b < 384) {
        const int base = (b - 256) * 256 + t;
        #pragma unroll
        for (int s = 0; s < 4; ++s) {
            const int idx = s * 32768 + base;
            const float4 v = *(const float4*)&x[(size_t)idx * 4];
            ushort4 h, l;
            h.x = bf16_hi(v.x); l.x = bf16_hi(v.x - bf16_back(h.x));
            h.y = bf16_hi(v.y); l.y = bf16_hi(v.y - bf16_back(h.y));
            h.z = bf16_hi(v.z); l.z = bf16_hi(v.z - bf16_back(h.z));
            h.w = bf16_hi(v.w); l.w = bf16_hi(v.w - bf16_back(h.w));
            *(ushort4*)&xh[(size_t)idx * 4] = h;
            *(ushort4*)&xl[(size_t)idx * 4] = l;
        }
    } else {
        // zero out: 32768 floats = 8192 float4 over 2 blocks
        const int base = (b - 384) * 4096 + t;
        const float4 z = make_float4(0.f, 0.f, 0.f, 0.f);
        #pragma unroll
        for (int s = 0; s < 16; ++s)
            *(float4*)&out[(size_t)(base + s * 256) * 4] = z;
    }
}

// ---------------------------------------------------------------------------
// MFMA GEMM, full-K, no partials. BM=32, BN=64, BK=64, grid 256 blocks
// (16 m-tiles x 16 n-tiles, XCD-mapped), 512 threads (8 waves).
// Split-bf16: M = xh*Th + xh*Tl + xl*Th. Double-buffered LDS (48KB),
// global_load_lds 16B with pre-swizzled source; ds_read swizzled (T2/G4).
// Output layout M2[kblk][512][16] so pairwise tiles are contiguous.
// ---------------------------------------------------------------------------
__global__ __launch_bounds__(512) void md_mfma_kernel(
    const unsigned short* __restrict__ xh, const unsigned short* __restrict__ xl,
    const unsigned short* __restrict__ Th, const unsigned short* __restrict__ Tl,
    float* __restrict__ M2) {
    // per buf (ushort offsets): Ah @0 (32x64), Al @2048, Bh @4096 (64x64), Bl @8192
    __shared__ __align__(16) unsigned short lds[2][12288];   // 2 x 24KB

    const int t = threadIdx.x, w = t >> 6, l = t & 63;
    const int b = blockIdx.x, xc = b & 7, s = b >> 3;
    const int mt = (xc & 1) * 8 + (s & 7);     // 0..15 (32-row m-tile)
    const int nt = (xc >> 1) * 4 + (s >> 3);   // 0..15 (64-col n-tile)

    // --- staging setup: 24 load-instrs of 1KB; wave w owns q = 3w..3w+2 ---
    // LDS gets (row, c) <- global (row, c ^ (row&7)); row&7 == l>>3 here.
    const int col16s = (l & 7) ^ (l >> 3);
    const unsigned short* gsrc[3];
    int ldsoff[3];
    #pragma unroll
    for (int j = 0; j < 3; ++j) {
        const int q = w * 3 + j;
        const unsigned short* base; int row0, seg;
        if (q < 4)       { base = xh + (size_t)mt * 32 * FF; row0 = q * 8;        seg = 0;    }
        else if (q < 8)  { base = xl + (size_t)mt * 32 * FF; row0 = (q - 4) * 8;  seg = 2048; }
        else if (q < 16) { base = Th + (size_t)nt * 64 * FF; row0 = (q - 8) * 8;  seg = 4096; }
        else             { base = Tl + (size_t)nt * 64 * FF; row0 = (q - 16) * 8; seg = 8192; }
        gsrc[j] = base + (size_t)(row0 + (l >> 3)) * FF + col16s * 8;
        ldsoff[j] = seg + row0 * 64;
    }

    const int lrow = l & 15, lkg = l >> 4;
    const int ar = (w >> 2) * 16 + lrow;       // A row 0..31
    const int br = (w & 3) * 16 + lrow;        // B row 0..63
    const int swa = ar & 7, swb = br & 7;

    f32x4 acc = {};

    #pragma unroll
    for (int j = 0; j < 3; ++j)
        __builtin_amdgcn_global_load_lds(
            (const __attribute__((address_space(1))) void*)gsrc[j],
            (__attribute__((address_space(3))) void*)&lds[0][ldsoff[j]], 16, 0, 0);
    __syncthreads();

    int buf = 0;
    for (int it = 0; it < 16; ++it) {
        if (it < 15) {
            #pragma unroll
            for (int j = 0; j < 3; ++j)
                __builtin_amdgcn_global_load_lds(
                    (const __attribute__((address_space(1))) void*)(gsrc[j] + (it + 1) * 64),
                    (__attribute__((address_space(3))) void*)&lds[buf ^ 1][ldsoff[j]], 16, 0, 0);
        }
        const unsigned short* L = lds[buf];
        #pragma unroll
        for (int ks = 0; ks < 2; ++ks) {
            const int cb = ks * 4 + lkg;               // k-chunk col16 0..7
            const int ca = (cb ^ swa) * 8, cc = (cb ^ swb) * 8;
            short8 ah = *(const short8*)&L[ar * 64 + ca];
            short8 al = *(const short8*)&L[2048 + ar * 64 + ca];
            short8 bh = *(const short8*)&L[4096 + br * 64 + cc];
            short8 bl = *(const short8*)&L[8192 + br * 64 + cc];
            acc = __builtin_amdgcn_mfma_f32_16x16x32_bf16(ah, bh, acc, 0, 0, 0);
            acc = __builtin_amdgcn_mfma_f32_16x16x32_bf16(ah, bl, acc, 0, 0, 0);
            acc = __builtin_amdgcn_mfma_f32_16x16x32_bf16(al, bh, acc, 0, 0, 0);
        }
        __syncthreads();
        buf ^= 1;
    }

    // C/D (m89): col = lane&15, row = (lane>>4)*4 + reg
    const int kblk = nt * 4 + (w & 3);
    const int rowb = mt * 32 + (w >> 2) * 16 + lkg * 4;
    #pragma unroll
    for (int rg = 0; rg < 4; ++rg)
        M2[((size_t)kblk * BB + rowb + rg) * KD + lrow] = acc[rg];
}

// ---------------------------------------------------------------------------
// Symmetric pairwise, single-M input in [kblk][512][16] layout: each tile is
// one contiguous 4KB read. 36 upper-tri tile-pairs x 64 k = 2304 blocks.
// ---------------------------------------------------------------------------
__global__ __launch_bounds__(256) void md_pairwise_sym_kernel(
    const float* __restrict__ M2, float* __restrict__ out) {
    __shared__ float Mi[64][20];         // padded: per-lane mi reads conflict-free
    __shared__ float Mj[64][16];         // broadcast reads, no pad needed
    __shared__ float et[64][65];
    __shared__ float part_row[4][64];
    __shared__ float part_col[4][64];

    const int bx = blockIdx.x;
    const int k = bx & 63;
    int p = bx >> 6;
    int it = 0;
    while (p >= 8 - it) { p -= 8 - it; ++it; }
    const int jt = it + p;
    const bool diag = (it == jt);
    const int t = threadIdx.x;

    const float* tileI = M2 + ((size_t)k * BB + it * 64) * KD;
    const float* tileJ = M2 + ((size_t)k * BB + jt * 64) * KD;
    {
        const int row = t >> 2, dg = (t & 3) * 4;
        const float4 a = *(const float4*)&tileI[t * 4];
        *(float4*)&Mi[row][dg] = a;
        const float4 c = *(const float4*)&tileJ[t * 4];
        *(float4*)&Mj[row][dg] = c;
    }
    __syncthreads();

    const int i = t & 63;
    const int wv = t >> 6;

    float mi[16];
    #pragma unroll
    for (int dg = 0; dg < 4; ++dg) {
        const float4 v = *(const float4*)&Mi[i][dg * 4];
        mi[dg * 4 + 0] = v.x; mi[dg * 4 + 1] = v.y;
        mi[dg * 4 + 2] = v.z; mi[dg * 4 + 3] = v.w;
    }

    float row_acc = 0.0f;
    #pragma unroll 4
    for (int jj = 0; jj < 16; ++jj) {
        const int j = wv * 16 + jj;      // wave-uniform -> broadcast reads
        const float4* mj = (const float4*)&Mj[j][0];
        const float4 v0 = mj[0], v1 = mj[1], v2 = mj[2], v3 = mj[3];
        float p0 = (fabsf(mi[0] - v0.x) + fabsf(mi[1] - v0.y)) +
                   (fabsf(mi[2] - v0.z) + fabsf(mi[3] - v0.w));
        float p1 = (fabsf(mi[4] - v1.x) + fabsf(mi[5] - v1.y)) +
                   (fabsf(mi[6] - v1.z) + fabsf(mi[7] - v1.w));
        float p2 = (fabsf(mi[8] - v2.x) + fabsf(mi[9] - v2.y)) +
                   (fabsf(mi[10] - v2.z) + fabsf(mi[11] - v2.w));
        float p3 = (fabsf(mi[12] - v3.x) + fabsf(mi[13] - v3.y)) +
                   (fabsf(mi[14] - v3.z) + fabsf(mi[15] - v3.w));
        const float e = __expf(-((p0 + p1) + (p2 + p3)));
        row_acc += e;
        et[i][j] = e;                    // banks (i+j)%32 -> 2-way, free
    }
    part_row[wv][i] = row_acc;
    __syncthreads();

    if (!diag) {
        const int j = t & 63;
        const int chunk = t >> 6;
        float col_acc = 0.0f;
        #pragma unroll
        for (int ii = 0; ii < 16; ++ii)
            col_acc += et[chunk * 16 + ii][j];
        part_col[chunk][j] = col_acc;
    }
    __syncthreads();

    if (t < 64) {
        float r = ((part_row[0][t] + part_row[1][t]) +
                   (part_row[2][t] + part_row[3][t])) - (diag ? 1.0f : 0.0f);
        atomicAdd(&out[(size_t)(it * 64 + t) * NK + k], r);
    } else if (t < 128 && !diag) {
        const int j = t - 64;
        float c = (part_col[0][j] + part_col[1][j]) +
                  (part_col[2][j] + part_col[3][j]);
        atomicAdd(&out[(size_t)(jt * 64 + j) * NK + k], c);
    }
}

extern "C" void kernel_launch(void* const* d_in, const int* in_sizes, int n_in,
                              void* d_out, int out_size, void* d_ws, size_t ws_size,
                              hipStream_t stream) {
    const float* x = (const float*)d_in[0];   // [512, 1024] f32
    const float* T = (const float*)d_in[1];   // [1024, 1024] f32
    float* out = (float*)d_out;               // [512, 64] f32

    unsigned short* xh = (unsigned short*)d_ws;         // 512x1024 bf16
    unsigned short* xl = xh + (size_t)BB * FF;
    unsigned short* Th = xl + (size_t)BB * FF;          // 1024x1024 bf16 [n][k]
    unsigned short* Tl = Th + (size_t)FF * FF;
    float* M2 = (float*)(Tl + (size_t)FF * FF);         // [64][512][16] f32

    md_prep_kernel<<<386, 256, 0, stream>>>(x, T, xh, xl, Th, Tl, out);
    md_mfma_kernel<<<dim3(256), 512, 0, stream>>>(xh, xl, Th, Tl, M2);
    md_pairwise_sym_kernel<<<dim3(36 * 64), 256, 0, stream>>>(M2, out);
}